// Round 8
// baseline (825.151 us; speedup 1.0000x reference)
//
#include <hip/hip_runtime.h>
#include <hip/hip_bf16.h>

#define M_TOT 8192
#define N_TOT 16384
#define K_TOT 4096
#define BM 256
#define BN 128
#define BK 64
#define NT (K_TOT / BK)  // 64 K-tiles

typedef int i32x4 __attribute__((ext_vector_type(4)));
typedef int i32x16 __attribute__((ext_vector_type(16)));
typedef __bf16 bf16x8 __attribute__((ext_vector_type(8)));
typedef float f32x4 __attribute__((ext_vector_type(4)));

#define GLOAD_LDS16(g, l)                                                     \
  __builtin_amdgcn_global_load_lds(                                           \
      (__attribute__((address_space(1))) const void*)(g),                     \
      (__attribute__((address_space(3))) void*)(l), 16, 0, 0)

__device__ __forceinline__ ushort f2bf_rne(float f) {
  unsigned u = __float_as_uint(f);
  u += 0x7FFFu + ((u >> 16) & 1u);
  return (ushort)(u >> 16);
}
__device__ __forceinline__ ushort sgn_bf16(float w) {
  return w > 0.f ? (ushort)0x3F80u : (w < 0.f ? (ushort)0xBF80u : (ushort)0u);
}

// ---------------- pass 1a: per-row amax + quantize x to i8 ----------------
__global__ void quant_x_kernel(const float* __restrict__ x,
                               char* __restrict__ xq, float* __restrict__ s) {
  int row = blockIdx.x;
  const float4* xr = (const float4*)(x + (size_t)row * K_TOT);
  int tid = threadIdx.x;
  float4 v[4];
  float amax = 0.f;
#pragma unroll
  for (int j = 0; j < 4; ++j) {
    v[j] = xr[j * 256 + tid];
    amax = fmaxf(amax, fmaxf(fmaxf(fabsf(v[j].x), fabsf(v[j].y)),
                             fmaxf(fabsf(v[j].z), fabsf(v[j].w))));
  }
#pragma unroll
  for (int o = 32; o > 0; o >>= 1) amax = fmaxf(amax, __shfl_xor(amax, o));
  __shared__ float wmax[4];
  if ((tid & 63) == 0) wmax[tid >> 6] = amax;
  __syncthreads();
  amax = fmaxf(fmaxf(wmax[0], wmax[1]), fmaxf(wmax[2], wmax[3]));
  float inv = amax > 0.f ? 127.0f / amax : 0.f;
  if (tid == 0) s[row] = amax * (1.0f / 127.0f);
  int* out = (int*)(xq + (size_t)row * K_TOT);
#pragma unroll
  for (int j = 0; j < 4; ++j) {
    int q0 = max(-127, min(127, __float2int_rn(v[j].x * inv)));
    int q1 = max(-127, min(127, __float2int_rn(v[j].y * inv)));
    int q2 = max(-127, min(127, __float2int_rn(v[j].z * inv)));
    int q3 = max(-127, min(127, __float2int_rn(v[j].w * inv)));
    out[j * 256 + tid] =
        (q0 & 255) | ((q1 & 255) << 8) | ((q2 & 255) << 16) | ((q3 & 255) << 24);
  }
}

// ---------------- pass 1b: W -> sign in i8 ----------------
__global__ void quant_w_kernel(const float* __restrict__ w,
                               char* __restrict__ wq, int n4) {
  int i = blockIdx.x * blockDim.x + threadIdx.x;
  int stride = gridDim.x * blockDim.x;
  for (; i < n4; i += stride) {
    float4 v = ((const float4*)w)[i];
    int q0 = v.x > 0.f ? 1 : (v.x < 0.f ? -1 : 0);
    int q1 = v.y > 0.f ? 1 : (v.y < 0.f ? -1 : 0);
    int q2 = v.z > 0.f ? 1 : (v.z < 0.f ? -1 : 0);
    int q3 = v.w > 0.f ? 1 : (v.w < 0.f ? -1 : 0);
    ((int*)wq)[i] =
        (q0 & 255) | ((q1 & 255) << 8) | ((q2 & 255) << 16) | ((q3 & 255) << 24);
  }
}

// ---------------- pass 2: i8 GEMM, triple-buffer, 1 barrier/tile ------------
// C[m][n] = s[m] * (sum_k A8[m][k]*W8[n][k]) + bias[n]   (i32 accum, exact)
// BM=256 BN=128 BK=64. 256 threads = 4 waves (2M x 2N), wave-tile 128x64 =
// 4mi x 2ni of 32x32 -> acc 128 AGPR; ~180 unified regs -> 2 waves/SIMD ->
// TWO independent blocks/CU. LDS: 3 bufs x (A 16KB + B 8KB) = 72KB/block
// (2 blocks = 144 <= 160).
//
// GROUP-SWIZZLE (round-7 verified: SQ_LDS_BANK_CONFLICT = 0): slab = 1024B
// groups = (32-row-group rg, K-half ks). A group base = (ks*8+rg)*1024 (16
// groups); B = 16384 + (ks*4+rg)*1024 (8 groups). In-group: 16B chunk of
// data (r in 0..31, c in 0..1) at slot (r&15)*4 + (((r>>4)|(c<<1)) ^
// (((r&15)>>1)&3)). Frag read (row=l31, c=hi) covers each group exactly
// once per ds_read_b128. gload_lds dest linear; permutation on global src.
//
// Tile body (buf = tt%3): STAGE(t+2 -> buf (tt+2)%3) [6 gload_lds];
// 12 ds_read_b128; 16 MFMA; vmcnt(6) [t+1's 6 landed, t+2's 6 in flight];
// s_barrier.  Single barrier: STAGE targets a buffer no wave reads this
// tile (3-buf rotation); buffer (tt+2)%3's last readers finished at tile
// tt-1, sealed by tile tt-1's barrier.
__global__ __launch_bounds__(256, 2) void gemm_i8_tri(
    const char* __restrict__ A, const char* __restrict__ B,
    const float* __restrict__ s, const float* __restrict__ bias,
    float* __restrict__ C) {
  __shared__ char lds[3][24576];  // [buf][A 16KB | B 8KB]

  // XCD supertile swizzle: 4096 blocks (32 bm x 128 bn); each XCD gets one
  // bn stripe (16 bn cols x all 32 bm rows) = 512 contiguous wg.
  int bid = blockIdx.x;
  int wg = (bid & 7) * 512 + (bid >> 3);
  int bnS = wg >> 9;
  int rem = wg & 511;
  int bm = rem >> 4;
  int bn = bnS * 16 + (rem & 15);
  int rowBase = bm * BM;
  int colBase = bn * BN;

  int t = threadIdx.x;
  int lane = t & 63;
  int wave = t >> 6;
  int wr = wave >> 1;  // 0..1 -> M half (128)
  int wc = wave & 1;   // 0..1 -> N half (64)
  int l31 = lane & 31;
  int hi = lane >> 5;

  // ---- staging sources (inverse of group-swizzle; dest byte = slot*16) ----
  // A: 1024 slots, thread t handles s = t + 256q, q=0..3.
  //    ks=(s>>9)&1, rg=(s>>6)&7, j=s&63: vrow=j>>2, craw=(j&3)^((j>>3)&3);
  //    r = rg*32+vrow+((craw&1)<<4); k = ks*32+((craw>>1)<<4).
  const char* gAp[4];
#pragma unroll
  for (int q = 0; q < 4; ++q) {
    int sA = t + 256 * q;
    int ksA = (sA >> 9) & 1, rgA = (sA >> 6) & 7;
    int j = sA & 63;
    int vrow = j >> 2;
    int craw = (j & 3) ^ ((j >> 3) & 3);
    int rA = rgA * 32 + vrow + ((craw & 1) << 4);
    int kA = ksA * 32 + ((craw >> 1) << 4);
    gAp[q] = A + (size_t)(rowBase + rA) * K_TOT + kA;
  }
  // B: 512 slots, thread t handles s = t + 256q, q=0..1.
  const char* gBp[2];
#pragma unroll
  for (int q = 0; q < 2; ++q) {
    int sB = t + 256 * q;
    int ksB = (sB >> 8) & 1, rgB = (sB >> 6) & 3;
    int j = sB & 63;
    int vrow = j >> 2;
    int craw = (j & 3) ^ ((j >> 3) & 3);
    int rB = rgB * 32 + vrow + ((craw & 1) << 4);
    int kB = ksB * 32 + ((craw >> 1) << 4);
    gBp[q] = B + (size_t)(colBase + rB) * K_TOT + kB;
  }

  // frag-read per-lane constant (in-group byte offset) — round-7 verified.
  int inb = ((((l31 & 15) << 2) |
              (((l31 >> 4) | (hi << 1)) ^ ((l31 >> 1) & 3)))) << 4;

  i32x16 acc[4][2] = {};

#define STAGE(kt_, buf_)                                                      \
  {                                                                           \
    size_t _o = (size_t)(kt_)*64;                                             \
    char* _d = &lds[buf_][0];                                                 \
    GLOAD_LDS16(gAp[0] + _o, _d + t * 16);                                    \
    GLOAD_LDS16(gAp[1] + _o, _d + 4096 + t * 16);                             \
    GLOAD_LDS16(gAp[2] + _o, _d + 8192 + t * 16);                             \
    GLOAD_LDS16(gAp[3] + _o, _d + 12288 + t * 16);                            \
    GLOAD_LDS16(gBp[0] + _o, _d + 16384 + t * 16);                            \
    GLOAD_LDS16(gBp[1] + _o, _d + 20480 + t * 16);                            \
  }

  // prologue: tiles 0 and 1
  STAGE(0, 0);
  STAGE(1, 1);
  asm volatile("s_waitcnt vmcnt(6)" ::: "memory");  // tile0 landed
  __builtin_amdgcn_s_barrier();

  int cur = 0;
  for (int tt = 0; tt < NT; ++tt) {
    int n2 = cur + 2 >= 3 ? cur - 1 : cur + 2;  // (cur+2)%3
    if (tt + 2 < NT) STAGE(tt + 2, n2);
    const char* la = &lds[cur][0];
    const char* lb = la + 16384;
    i32x4 af[4], bf[2];
#pragma unroll
    for (int ks = 0; ks < 2; ++ks) {
#pragma unroll
      for (int mi = 0; mi < 4; ++mi)
        af[mi] = *(const i32x4*)(la + ((ks * 8 + wr * 4 + mi) << 10) + inb);
#pragma unroll
      for (int ni = 0; ni < 2; ++ni)
        bf[ni] = *(const i32x4*)(lb + ((ks * 4 + wc * 2 + ni) << 10) + inb);
      __builtin_amdgcn_s_setprio(1);
#pragma unroll
      for (int mi = 0; mi < 4; ++mi)
#pragma unroll
        for (int ni = 0; ni < 2; ++ni)
          acc[mi][ni] = __builtin_amdgcn_mfma_i32_32x32x32_i8(
              af[mi], bf[ni], acc[mi][ni], 0, 0, 0);
      __builtin_amdgcn_s_setprio(0);
    }
    if (tt + 2 < NT) {
      asm volatile("s_waitcnt vmcnt(6)" ::: "memory");  // tile t+1 landed
    } else if (tt + 1 < NT) {
      asm volatile("s_waitcnt vmcnt(0)" ::: "memory");
    }
    __builtin_amdgcn_s_barrier();
    cur = cur == 2 ? 0 : cur + 1;
  }

#undef STAGE

  // epilogue: y = s[m] * acc + bias[n]
  // C/D 32x32: col = lane&31, row = (reg&3) + 8*(reg>>2) + 4*(lane>>5)
#pragma unroll
  for (int mi = 0; mi < 4; ++mi) {
#pragma unroll
    for (int ni = 0; ni < 2; ++ni) {
      int gc = colBase + wc * 64 + ni * 32 + l31;
      float bv = bias[gc];
#pragma unroll
      for (int rg = 0; rg < 16; ++rg) {
        int rowIn = (rg & 3) + 8 * (rg >> 2) + 4 * hi;
        int gr = rowBase + wr * 128 + mi * 32 + rowIn;
        C[(size_t)gr * N_TOT + gc] = (float)acc[mi][ni][rg] * s[gr] + bv;
      }
    }
  }
}

// ---------------- fallback (ws too small): fused bf16 conversion GEMM --------
__global__ void gemm_fused_kernel(const float* __restrict__ A,
                                  const float* __restrict__ W,
                                  const float* __restrict__ bias,
                                  float* __restrict__ C) {
  __shared__ ushort lsA[128 * 32];
  __shared__ ushort lsB[128 * 32];

  int nwg = gridDim.x;
  int bid = blockIdx.x;
  int wg = (bid & 7) * (nwg >> 3) + (bid >> 3);
  const int NBN = N_TOT / 128;
  int bm = wg / NBN;
  int bn = wg % NBN;
  int rowBase = bm * 128;
  int colBase = bn * 128;

  int t = threadIdx.x;
  int lane = t & 63;
  int wave = t >> 6;
  int wm = (wave >> 1) * 64;
  int wn = (wave & 1) * 64;

  f32x4 acc[4][4] = {};

  int srow = t >> 3;
  int scol = (t & 7) * 4;
  int fr = lane & 15;
  int koff = (lane >> 4) * 8;

  for (int k0 = 0; k0 < K_TOT; k0 += 32) {
    float4 va[4], vb[4];
#pragma unroll
    for (int r = 0; r < 4; ++r) {
      va[r] = *(const float4*)&A[(size_t)(rowBase + r * 32 + srow) * K_TOT + k0 + scol];
      vb[r] = *(const float4*)&W[(size_t)(colBase + r * 32 + srow) * K_TOT + k0 + scol];
    }
    __syncthreads();
#pragma unroll
    for (int r = 0; r < 4; ++r) {
      int e = r * 1024 + t * 4;
      ushort4 oa, ob;
      oa.x = f2bf_rne(va[r].x); oa.y = f2bf_rne(va[r].y);
      oa.z = f2bf_rne(va[r].z); oa.w = f2bf_rne(va[r].w);
      ob.x = sgn_bf16(vb[r].x); ob.y = sgn_bf16(vb[r].y);
      ob.z = sgn_bf16(vb[r].z); ob.w = sgn_bf16(vb[r].w);
      *(ushort4*)&lsA[e] = oa;
      *(ushort4*)&lsB[e] = ob;
    }
    __syncthreads();

    bf16x8 af[4], bfr[4];
#pragma unroll
    for (int i = 0; i < 4; ++i)
      af[i] = *(const bf16x8*)&lsA[(wm + i * 16 + fr) * 32 + koff];
#pragma unroll
    for (int j = 0; j < 4; ++j)
      bfr[j] = *(const bf16x8*)&lsB[(wn + j * 16 + fr) * 32 + koff];

#pragma unroll
    for (int i = 0; i < 4; ++i)
#pragma unroll
      for (int j = 0; j < 4; ++j)
        acc[i][j] = __builtin_amdgcn_mfma_f32_16x16x32_bf16(af[i], bfr[j],
                                                            acc[i][j], 0, 0, 0);
  }

  int orow0 = rowBase + wm + ((lane >> 4) << 2);
  int ocol0 = colBase + wn + (lane & 15);
#pragma unroll
  for (int i = 0; i < 4; ++i) {
#pragma unroll
    for (int j = 0; j < 4; ++j) {
      int col = ocol0 + j * 16;
      float bv = bias[col];
#pragma unroll
      for (int rg = 0; rg < 4; ++rg) {
        int row = orow0 + i * 16 + rg;
        C[(size_t)row * N_TOT + col] = acc[i][j][rg] + bv;
      }
    }
  }
}

extern "C" void kernel_launch(void* const* d_in, const int* in_sizes, int n_in,
                              void* d_out, int out_size, void* d_ws,
                              size_t ws_size, hipStream_t stream) {
  const float* x = (const float*)d_in[0];
  const float* W = (const float*)d_in[1];
  const float* b = (const float*)d_in[2];
  float* out = (float*)d_out;

  const size_t xq_bytes = (size_t)M_TOT * K_TOT;           // 33.5 MB
  const size_t wq_bytes = (size_t)N_TOT * K_TOT;           // 67.1 MB
  const size_t need = xq_bytes + wq_bytes + M_TOT * 4;     // ~101 MB

  if (ws_size >= need) {
    char* xq = (char*)d_ws;
    char* wq = xq + xq_bytes;
    float* s = (float*)(wq + wq_bytes);
    quant_x_kernel<<<M_TOT, 256, 0, stream>>>(x, xq, s);
    quant_w_kernel<<<2048, 256, 0, stream>>>(W, wq, (int)(wq_bytes / 4));
    const int nblocks = (M_TOT / BM) * (N_TOT / BN);  // 4096
    gemm_i8_tri<<<nblocks, 256, 0, stream>>>(xq, wq, s, b, out);
  } else {
    const int nblocks = (M_TOT / 128) * (N_TOT / 128);
    gemm_fused_kernel<<<nblocks, 256, 0, stream>>>(x, W, b, out);
  }
}

// Round 9
// 812.968 us; speedup vs baseline: 1.0150x; 1.0150x over previous
//
#include <hip/hip_runtime.h>
#include <hip/hip_bf16.h>

#define M_TOT 8192
#define N_TOT 16384
#define K_TOT 4096
#define BM 128
#define BN 256
#define BK 64
#define NT (K_TOT / BK)  // 64 K-tiles

typedef int i32x4 __attribute__((ext_vector_type(4)));
typedef int i32x16 __attribute__((ext_vector_type(16)));
typedef __bf16 bf16x8 __attribute__((ext_vector_type(8)));
typedef float f32x4 __attribute__((ext_vector_type(4)));

#define GLOAD_LDS16(g, l)                                                     \
  __builtin_amdgcn_global_load_lds(                                           \
      (__attribute__((address_space(1))) const void*)(g),                     \
      (__attribute__((address_space(3))) void*)(l), 16, 0, 0)

__device__ __forceinline__ ushort f2bf_rne(float f) {
  unsigned u = __float_as_uint(f);
  u += 0x7FFFu + ((u >> 16) & 1u);
  return (ushort)(u >> 16);
}
__device__ __forceinline__ ushort sgn_bf16(float w) {
  return w > 0.f ? (ushort)0x3F80u : (w < 0.f ? (ushort)0xBF80u : (ushort)0u);
}

// ---------------- pass 1a: per-row amax + quantize x to i8 ----------------
__global__ void quant_x_kernel(const float* __restrict__ x,
                               char* __restrict__ xq, float* __restrict__ s) {
  int row = blockIdx.x;
  const float4* xr = (const float4*)(x + (size_t)row * K_TOT);
  int tid = threadIdx.x;
  float4 v[4];
  float amax = 0.f;
#pragma unroll
  for (int j = 0; j < 4; ++j) {
    v[j] = xr[j * 256 + tid];
    amax = fmaxf(amax, fmaxf(fmaxf(fabsf(v[j].x), fabsf(v[j].y)),
                             fmaxf(fabsf(v[j].z), fabsf(v[j].w))));
  }
#pragma unroll
  for (int o = 32; o > 0; o >>= 1) amax = fmaxf(amax, __shfl_xor(amax, o));
  __shared__ float wmax[4];
  if ((tid & 63) == 0) wmax[tid >> 6] = amax;
  __syncthreads();
  amax = fmaxf(fmaxf(wmax[0], wmax[1]), fmaxf(wmax[2], wmax[3]));
  float inv = amax > 0.f ? 127.0f / amax : 0.f;
  if (tid == 0) s[row] = amax * (1.0f / 127.0f);
  int* out = (int*)(xq + (size_t)row * K_TOT);
#pragma unroll
  for (int j = 0; j < 4; ++j) {
    int q0 = max(-127, min(127, __float2int_rn(v[j].x * inv)));
    int q1 = max(-127, min(127, __float2int_rn(v[j].y * inv)));
    int q2 = max(-127, min(127, __float2int_rn(v[j].z * inv)));
    int q3 = max(-127, min(127, __float2int_rn(v[j].w * inv)));
    out[j * 256 + tid] =
        (q0 & 255) | ((q1 & 255) << 8) | ((q2 & 255) << 16) | ((q3 & 255) << 24);
  }
}

// ---------------- pass 1b: W -> sign in i8 ----------------
__global__ void quant_w_kernel(const float* __restrict__ w,
                               char* __restrict__ wq, int n4) {
  int i = blockIdx.x * blockDim.x + threadIdx.x;
  int stride = gridDim.x * blockDim.x;
  for (; i < n4; i += stride) {
    float4 v = ((const float4*)w)[i];
    int q0 = v.x > 0.f ? 1 : (v.x < 0.f ? -1 : 0);
    int q1 = v.y > 0.f ? 1 : (v.y < 0.f ? -1 : 0);
    int q2 = v.z > 0.f ? 1 : (v.z < 0.f ? -1 : 0);
    int q3 = v.w > 0.f ? 1 : (v.w < 0.f ? -1 : 0);
    ((int*)wq)[i] =
        (q0 & 255) | ((q1 & 255) << 8) | ((q2 & 255) << 16) | ((q3 & 255) << 24);
  }
}

// ---------------- pass 2: i8 GEMM, tri-buffer, 16 waves/CU, no setprio ------
// C[m][n] = s[m] * (sum_k A8[m][k]*W8[n][k]) + bias[n]   (i32 accum, exact)
// BM=128 BN=256 BK=64. 512 threads = 8 waves (2M x 4N), wave-tile 64x64 =
// 2x2 of 32x32 -> acc 64 AGPR; ~120 unified regs, launch_bounds(512,4) ->
// 4 waves/SIMD = 2 blocks/CU (16 waves/CU). LDS: 3 bufs x (A 8KB + B 16KB)
// = 72KB/block; 2 blocks = 144 <= 160.
//
// GROUP-SWIZZLE (R7-verified SQ_LDS_BANK_CONFLICT = 0): buf = 1024B groups
// (32-row-group rg, K-half ks). A base = (ks*4+rg)*1024 (8 groups, 128 rows);
// B base = 8192 + (ks*8+rg)*1024 (16 groups, 256 rows). In-group: 16B chunk
// of (r in 0..31, c in 0..1) at slot (r&15)*4 + (((r>>4)|(c<<1)) ^
// (((r&15)>>1)&3)). Frag read (row=l31, c=hi) covers each group exactly once
// per ds_read_b128. gload_lds dest linear; permutation on global source.
//
// Tile body (buf rotation cur -> tt%3): STAGE(t+2) [3 gload_lds]; ALL 8 frag
// reads issued up-front (no setprio, no fences) so MFMA-ks0 overlaps ks1's
// in-flight reads; 8 MFMA; vmcnt(3) [t+1's 3 landed, t+2's 3 in flight];
// s_barrier. Single barrier: STAGE targets the buffer whose last readers
// finished at tile tt-1 (sealed by tt-1's barrier + reads consumed by MFMAs
// preceding it).
__global__ __launch_bounds__(512, 4) void gemm_i8_tri16(
    const char* __restrict__ A, const char* __restrict__ B,
    const float* __restrict__ s, const float* __restrict__ bias,
    float* __restrict__ C) {
  __shared__ char lds[3][24576];  // [buf][A 8KB | B 16KB]

  // XCD supertile swizzle: 4096 blocks (64 bm x 64 bn); each XCD gets one
  // bn stripe (8 bn cols x all 64 bm rows) = 512 contiguous wg.
  int bid = blockIdx.x;
  int wg = (bid & 7) * 512 + (bid >> 3);
  int bnS = wg >> 9;
  int rem = wg & 511;
  int bm = rem >> 3;
  int bn = bnS * 8 + (rem & 7);
  int rowBase = bm * BM;
  int colBase = bn * BN;

  int t = threadIdx.x;
  int lane = t & 63;
  int wave = t >> 6;
  int wr = wave >> 2;  // 0..1 -> M half (64)
  int wc = wave & 3;   // 0..3 -> N quarter (64)
  int l31 = lane & 31;
  int hi = lane >> 5;

  // ---- staging sources (inverse of group-swizzle; dest byte = slot*16) ----
  // A: 512 slots, thread t owns slot t: ks=(t>>8)&1, rg=(t>>6)&3, j=t&63;
  //    vrow=j>>2, craw=(j&3)^((j>>3)&3);
  //    r = rg*32+vrow+((craw&1)<<4); k = ks*32+((craw>>1)<<4).
  {
  }
  int jA = t & 63;
  int vrowA = jA >> 2;
  int crawA = (jA & 3) ^ ((jA >> 3) & 3);
  int rA = ((t >> 6) & 3) * 32 + vrowA + ((crawA & 1) << 4);
  int kA = ((t >> 8) & 1) * 32 + ((crawA >> 1) << 4);
  const char* gA = A + (size_t)(rowBase + rA) * K_TOT + kA;
  // B: 1024 slots, thread t owns s0=t (ks=0) and s1=t+512 (ks=1, same rg/j):
  int rB = ((t >> 6) & 7) * 32 + vrowA + ((crawA & 1) << 4);
  int kB = (crawA >> 1) << 4;
  const char* gB0 = B + (size_t)(colBase + rB) * K_TOT + kB;
  const char* gB1 = gB0 + 32;  // ks=1

  // frag-read per-lane constant (in-group byte offset) — R7-verified.
  int inb = ((((l31 & 15) << 2) |
              (((l31 >> 4) | (hi << 1)) ^ ((l31 >> 1) & 3)))) << 4;

  i32x16 acc[2][2] = {};

#define STAGE(kt_, buf_)                                                      \
  {                                                                           \
    size_t _o = (size_t)(kt_)*64;                                             \
    char* _d = &lds[buf_][0];                                                 \
    GLOAD_LDS16(gA + _o, _d + t * 16);                                        \
    GLOAD_LDS16(gB0 + _o, _d + 8192 + t * 16);                                \
    GLOAD_LDS16(gB1 + _o, _d + 16384 + t * 16);                               \
  }

  // prologue: tiles 0 and 1
  STAGE(0, 0);
  STAGE(1, 1);
  asm volatile("s_waitcnt vmcnt(3)" ::: "memory");  // tile0 landed
  __builtin_amdgcn_s_barrier();

  int cur = 0;
  for (int tt = 0; tt < NT; ++tt) {
    int n2 = cur + 2 >= 3 ? cur - 1 : cur + 2;  // (cur+2)%3
    if (tt + 2 < NT) STAGE(tt + 2, n2);
    const char* la = &lds[cur][0];
    // all 8 frag reads up-front; compiler emits counted lgkmcnt so ks0 MFMAs
    // run while ks1 reads are still in flight
    i32x4 a0[2], b0[2], a1[2], b1[2];
#pragma unroll
    for (int mi = 0; mi < 2; ++mi)
      a0[mi] = *(const i32x4*)(la + ((wr * 2 + mi) << 10) + inb);
#pragma unroll
    for (int ni = 0; ni < 2; ++ni)
      b0[ni] = *(const i32x4*)(la + 8192 + ((wc * 2 + ni) << 10) + inb);
#pragma unroll
    for (int mi = 0; mi < 2; ++mi)
      a1[mi] = *(const i32x4*)(la + ((4 + wr * 2 + mi) << 10) + inb);
#pragma unroll
    for (int ni = 0; ni < 2; ++ni)
      b1[ni] = *(const i32x4*)(la + 8192 + ((8 + wc * 2 + ni) << 10) + inb);
#pragma unroll
    for (int mi = 0; mi < 2; ++mi)
#pragma unroll
      for (int ni = 0; ni < 2; ++ni)
        acc[mi][ni] = __builtin_amdgcn_mfma_i32_32x32x32_i8(a0[mi], b0[ni],
                                                            acc[mi][ni], 0, 0, 0);
#pragma unroll
    for (int mi = 0; mi < 2; ++mi)
#pragma unroll
      for (int ni = 0; ni < 2; ++ni)
        acc[mi][ni] = __builtin_amdgcn_mfma_i32_32x32x32_i8(a1[mi], b1[ni],
                                                            acc[mi][ni], 0, 0, 0);
    if (tt + 2 < NT) {
      asm volatile("s_waitcnt vmcnt(3)" ::: "memory");  // tile t+1 landed
    } else if (tt + 1 < NT) {
      asm volatile("s_waitcnt vmcnt(0)" ::: "memory");
    }
    __builtin_amdgcn_s_barrier();
    cur = cur == 2 ? 0 : cur + 1;
  }

#undef STAGE

  // epilogue: y = s[m] * acc + bias[n]
  // C/D 32x32: col = lane&31, row = (reg&3) + 8*(reg>>2) + 4*(lane>>5)
#pragma unroll
  for (int mi = 0; mi < 2; ++mi) {
#pragma unroll
    for (int ni = 0; ni < 2; ++ni) {
      int gc = colBase + wc * 64 + ni * 32 + l31;
      float bv = bias[gc];
#pragma unroll
      for (int rg = 0; rg < 16; ++rg) {
        int rowIn = (rg & 3) + 8 * (rg >> 2) + 4 * hi;
        int gr = rowBase + wr * 64 + mi * 32 + rowIn;
        C[(size_t)gr * N_TOT + gc] = (float)acc[mi][ni][rg] * s[gr] + bv;
      }
    }
  }
}

// ---------------- fallback (ws too small): fused bf16 conversion GEMM --------
__global__ void gemm_fused_kernel(const float* __restrict__ A,
                                  const float* __restrict__ W,
                                  const float* __restrict__ bias,
                                  float* __restrict__ C) {
  __shared__ ushort lsA[128 * 32];
  __shared__ ushort lsB[128 * 32];

  int nwg = gridDim.x;
  int bid = blockIdx.x;
  int wg = (bid & 7) * (nwg >> 3) + (bid >> 3);
  const int NBN = N_TOT / 128;
  int bm = wg / NBN;
  int bn = wg % NBN;
  int rowBase = bm * 128;
  int colBase = bn * 128;

  int t = threadIdx.x;
  int lane = t & 63;
  int wave = t >> 6;
  int wm = (wave >> 1) * 64;
  int wn = (wave & 1) * 64;

  f32x4 acc[4][4] = {};

  int srow = t >> 3;
  int scol = (t & 7) * 4;
  int fr = lane & 15;
  int koff = (lane >> 4) * 8;

  for (int k0 = 0; k0 < K_TOT; k0 += 32) {
    float4 va[4], vb[4];
#pragma unroll
    for (int r = 0; r < 4; ++r) {
      va[r] = *(const float4*)&A[(size_t)(rowBase + r * 32 + srow) * K_TOT + k0 + scol];
      vb[r] = *(const float4*)&W[(size_t)(colBase + r * 32 + srow) * K_TOT + k0 + scol];
    }
    __syncthreads();
#pragma unroll
    for (int r = 0; r < 4; ++r) {
      int e = r * 1024 + t * 4;
      ushort4 oa, ob;
      oa.x = f2bf_rne(va[r].x); oa.y = f2bf_rne(va[r].y);
      oa.z = f2bf_rne(va[r].z); oa.w = f2bf_rne(va[r].w);
      ob.x = sgn_bf16(vb[r].x); ob.y = sgn_bf16(vb[r].y);
      ob.z = sgn_bf16(vb[r].z); ob.w = sgn_bf16(vb[r].w);
      *(ushort4*)&lsA[e] = oa;
      *(ushort4*)&lsB[e] = ob;
    }
    __syncthreads();

    bf16x8 af[4], bfr[4];
#pragma unroll
    for (int i = 0; i < 4; ++i)
      af[i] = *(const bf16x8*)&lsA[(wm + i * 16 + fr) * 32 + koff];
#pragma unroll
    for (int j = 0; j < 4; ++j)
      bfr[j] = *(const bf16x8*)&lsB[(wn + j * 16 + fr) * 32 + koff];

#pragma unroll
    for (int i = 0; i < 4; ++i)
#pragma unroll
      for (int j = 0; j < 4; ++j)
        acc[i][j] = __builtin_amdgcn_mfma_f32_16x16x32_bf16(af[i], bfr[j],
                                                            acc[i][j], 0, 0, 0);
  }

  int orow0 = rowBase + wm + ((lane >> 4) << 2);
  int ocol0 = colBase + wn + (lane & 15);
#pragma unroll
  for (int i = 0; i < 4; ++i) {
#pragma unroll
    for (int j = 0; j < 4; ++j) {
      int col = ocol0 + j * 16;
      float bv = bias[col];
#pragma unroll
      for (int rg = 0; rg < 4; ++rg) {
        int row = orow0 + i * 16 + rg;
        C[(size_t)row * N_TOT + col] = acc[i][j][rg] + bv;
      }
    }
  }
}

extern "C" void kernel_launch(void* const* d_in, const int* in_sizes, int n_in,
                              void* d_out, int out_size, void* d_ws,
                              size_t ws_size, hipStream_t stream) {
  const float* x = (const float*)d_in[0];
  const float* W = (const float*)d_in[1];
  const float* b = (const float*)d_in[2];
  float* out = (float*)d_out;

  const size_t xq_bytes = (size_t)M_TOT * K_TOT;           // 33.5 MB
  const size_t wq_bytes = (size_t)N_TOT * K_TOT;           // 67.1 MB
  const size_t need = xq_bytes + wq_bytes + M_TOT * 4;     // ~101 MB

  if (ws_size >= need) {
    char* xq = (char*)d_ws;
    char* wq = xq + xq_bytes;
    float* s = (float*)(wq + wq_bytes);
    quant_x_kernel<<<M_TOT, 256, 0, stream>>>(x, xq, s);
    quant_w_kernel<<<2048, 256, 0, stream>>>(W, wq, (int)(wq_bytes / 4));
    const int nblocks = (M_TOT / BM) * (N_TOT / BN);  // 4096
    gemm_i8_tri16<<<nblocks, 512, 0, stream>>>(xq, wq, s, b, out);
  } else {
    const int nblocks = (M_TOT / 128) * (N_TOT / 128);
    gemm_fused_kernel<<<nblocks, 256, 0, stream>>>(x, W, b, out);
  }
}

// Round 10
// 744.865 us; speedup vs baseline: 1.1078x; 1.0914x over previous
//
#include <hip/hip_runtime.h>
#include <hip/hip_bf16.h>

#define M_TOT 8192
#define N_TOT 16384
#define K_TOT 4096
#define BM 256
#define BN 128
#define BK 64
#define NT (K_TOT / BK)  // 64 K-tiles

typedef int i32x4 __attribute__((ext_vector_type(4)));
typedef int i32x16 __attribute__((ext_vector_type(16)));
typedef __bf16 bf16x8 __attribute__((ext_vector_type(8)));
typedef float f32x4 __attribute__((ext_vector_type(4)));

#define GLOAD_LDS16(g, l)                                                     \
  __builtin_amdgcn_global_load_lds(                                           \
      (__attribute__((address_space(1))) const void*)(g),                     \
      (__attribute__((address_space(3))) void*)(l), 16, 0, 0)

__device__ __forceinline__ ushort f2bf_rne(float f) {
  unsigned u = __float_as_uint(f);
  u += 0x7FFFu + ((u >> 16) & 1u);
  return (ushort)(u >> 16);
}
__device__ __forceinline__ ushort sgn_bf16(float w) {
  return w > 0.f ? (ushort)0x3F80u : (w < 0.f ? (ushort)0xBF80u : (ushort)0u);
}

// ============ Fragment-order (tiled) operand layouts ============
// A_tiled: chunk (r32, kt, ks) at ((r32*128) + kt*2 + ks)*1024;
//   within chunk, lane l (=hi*32+l31) holds bytes l*16..+15 =
//   A[r32*32 + l31][kt*64 + ks*32 + hi*16 .. +16).   (33.5 MB)
// B_tiled: chunk (n32, kt, ks) at ((n32*64 + kt)*2 + ks)*1024;
//   lane l holds B[n32*32 + l31][kt*64 + ks*32 + hi*16 .. +16). (67.1 MB)
// Both are exactly the mfma_i32_32x32x32_i8 operand fragments -> GEMM-side
// LDS reads and buffer_loads are lane-linear (conflict-free / coalesced).

// ---------------- pass 1a: per-row amax + quantize x -> A_tiled --------------
__global__ void quant_x_kernel(const float* __restrict__ x,
                               char* __restrict__ At, float* __restrict__ s) {
  int row = blockIdx.x;
  int tid = threadIdx.x;
  const float4* xr = (const float4*)(x + (size_t)row * K_TOT + tid * 16);
  float4 v[4];
  float amax = 0.f;
#pragma unroll
  for (int j = 0; j < 4; ++j) {
    v[j] = xr[j];  // 16 contiguous floats per thread (64B)
    amax = fmaxf(amax, fmaxf(fmaxf(fabsf(v[j].x), fabsf(v[j].y)),
                             fmaxf(fabsf(v[j].z), fabsf(v[j].w))));
  }
#pragma unroll
  for (int o = 32; o > 0; o >>= 1) amax = fmaxf(amax, __shfl_xor(amax, o));
  __shared__ float wmax[4];
  if ((tid & 63) == 0) wmax[tid >> 6] = amax;
  __syncthreads();
  amax = fmaxf(fmaxf(wmax[0], wmax[1]), fmaxf(wmax[2], wmax[3]));
  float inv = amax > 0.f ? 127.0f / amax : 0.f;
  if (tid == 0) s[row] = amax * (1.0f / 127.0f);
  int q[16];
#pragma unroll
  for (int j = 0; j < 4; ++j) {
    q[j * 4 + 0] = max(-127, min(127, __float2int_rn(v[j].x * inv)));
    q[j * 4 + 1] = max(-127, min(127, __float2int_rn(v[j].y * inv)));
    q[j * 4 + 2] = max(-127, min(127, __float2int_rn(v[j].z * inv)));
    q[j * 4 + 3] = max(-127, min(127, __float2int_rn(v[j].w * inv)));
  }
  int4 o4;
  int* op = (int*)&o4;
#pragma unroll
  for (int j = 0; j < 4; ++j)
    op[j] = (q[j * 4] & 255) | ((q[j * 4 + 1] & 255) << 8) |
            ((q[j * 4 + 2] & 255) << 16) | ((q[j * 4 + 3] & 255) << 24);
  // dest: thread tid covers k-chunk16 tid: kt=tid>>2, ks=(tid>>1)&1, hi=tid&1
  int r32 = row >> 5, l31 = row & 31;
  int kt = tid >> 2, ks = (tid >> 1) & 1, hi = tid & 1;
  size_t dst = ((size_t)(r32 * 128 + kt * 2 + ks) << 10) + ((hi * 32 + l31) << 4);
  *(int4*)(At + dst) = o4;
}

// ---------------- pass 1b: W -> sign i8 in B_tiled ----------------
__global__ void quant_w_kernel(const float* __restrict__ w,
                               char* __restrict__ Bt) {
  int n32 = blockIdx.x;  // 512 blocks
  int t = threadIdx.x;
#pragma unroll 4
  for (int i = 0; i < 32; ++i) {
    int c = i * 256 + t;  // 0..8191: kt = c>>7, ks = (c>>6)&1, l = c&63
    int kt = c >> 7, ks = (c >> 6) & 1, l = c & 63;
    int n = n32 * 32 + (l & 31);
    int k = kt * 64 + ks * 32 + (l >> 5) * 16;
    const float4* src = (const float4*)(w + (size_t)n * K_TOT + k);
    int4 o4;
    int* op = (int*)&o4;
#pragma unroll
    for (int j = 0; j < 4; ++j) {
      float4 v = src[j];
      int q0 = v.x > 0.f ? 1 : (v.x < 0.f ? -1 : 0);
      int q1 = v.y > 0.f ? 1 : (v.y < 0.f ? -1 : 0);
      int q2 = v.z > 0.f ? 1 : (v.z < 0.f ? -1 : 0);
      int q3 = v.w > 0.f ? 1 : (v.w < 0.f ? -1 : 0);
      op[j] = (q0 & 255) | ((q1 & 255) << 8) | ((q2 & 255) << 16) |
              ((q3 & 255) << 24);
    }
    *(int4*)(Bt + ((size_t)n32 << 17) + ((size_t)c << 4)) = o4;
  }
}

// ---------------- pass 2: i8 GEMM, A via LDS (linear), B via registers ------
// C[m][n] = s[m]*(sum_k A8[m][k]*W8[n][k]) + bias[n]  (i32 accum, exact)
// BM=256 BN=128 BK=64. 256 threads = 4 waves (2M x 2N), wave-tile 128x64 =
// 4mi x 2ni of 32x32 (acc 128 AGPR; ~200 unified regs -> 2 waves/SIMD,
// 2 blocks/CU). LDS: 4 bufs x 16KB (A only) = 64KB/block; 2 blocks = 128KB.
// Per tile per wave: 4 gload_lds (A stage) + 4 buffer_load (B frags, 1KB
// coalesced) + 8 ds_read_b128 (lane-linear, conflict-free) + 16 MFMA.
// Pipes: LDS ~1150 cyc/CU-tile, VMEM ~1140, MFMA 1170 -> balanced.
// Schedule per tile t (buf t&3, breg t&1):
//   STAGE_A(t+2 -> buf (t+2)&3); LOADB(t+1 -> breg (t+1)&1);
//   vmcnt(8) [leaves exactly those 8; confirms A(t+1) landed + B(t) regs];
//   8 ds_read + 16 MFMA (compiler-counted lgkmcnt); s_barrier.
// Safety: buf (t+2)&3's last readers ran at tile t-2, sealed by 2 barriers.
__global__ __launch_bounds__(256, 2) void gemm_i8_reg(
    const char* __restrict__ At, const char* __restrict__ Bt,
    const float* __restrict__ s, const float* __restrict__ bias,
    float* __restrict__ C) {
  __shared__ char lds[4][16384];

  // XCD stripe swizzle: 4096 blocks (32 bm x 128 bn); stripe = 16 bn x 32 bm.
  int bid = blockIdx.x;
  int wg = (bid & 7) * 512 + (bid >> 3);
  int bnS = wg >> 9;
  int rem = wg & 511;
  int bm = rem >> 4;
  int bn = bnS * 16 + (rem & 15);
  int rowBase = bm * BM;
  int colBase = bn * BN;

  int t = threadIdx.x;
  int lane = t & 63;
  int wave = t >> 6;
  int wr = wave >> 1;  // 0..1 -> M half (128)
  int wc = wave & 1;   // 0..1 -> N half (64)
  int l31 = lane & 31;
  int hi = lane >> 5;

  // A staging: LDS slab group g = ks*8 + rg (rg = r32 within tile, 0..7);
  // thread t covers slots s = t + 256q; src chunk = (bm*8+rg)*128 + kt*2+ks.
  const char* gAp[4];
#pragma unroll
  for (int q = 0; q < 4; ++q) {
    int ss = t + 256 * q;
    int g = ss >> 6;
    int ks = g >> 3, rg = g & 7;
    gAp[q] = At + ((size_t)((bm * 8 + rg) * 128 + ks) << 10) + ((ss & 63) << 4);
  }
  // B frag bases per ni (kt/ks offsets added per tile)
  const char* gBp[2];
#pragma unroll
  for (int ni = 0; ni < 2; ++ni)
    gBp[ni] = Bt + ((size_t)(bn * 4 + wc * 2 + ni) << 17) + (lane << 4);

  i32x16 acc[4][2] = {};
  i32x4 brA[2][2], brB[2][2];  // [ks][ni], two static sets

#define STAGE_A(kt_, buf_)                                                    \
  {                                                                           \
    size_t _o = (size_t)(kt_) << 11;                                          \
    GLOAD_LDS16(gAp[0] + _o, &lds[buf_][t * 16]);                             \
    GLOAD_LDS16(gAp[1] + _o, &lds[buf_][4096 + t * 16]);                      \
    GLOAD_LDS16(gAp[2] + _o, &lds[buf_][8192 + t * 16]);                      \
    GLOAD_LDS16(gAp[3] + _o, &lds[buf_][12288 + t * 16]);                     \
  }
#define LOADB(kt_, dst)                                                       \
  {                                                                           \
    size_t _o = (size_t)(kt_) << 11;                                          \
    dst[0][0] = *(const i32x4*)(gBp[0] + _o);                                 \
    dst[0][1] = *(const i32x4*)(gBp[1] + _o);                                 \
    dst[1][0] = *(const i32x4*)(gBp[0] + _o + 1024);                          \
    dst[1][1] = *(const i32x4*)(gBp[1] + _o + 1024);                          \
  }
#define COMPUTE(buf_, bset)                                                   \
  {                                                                           \
    const char* _la = &lds[buf_][0];                                          \
    _Pragma("unroll") for (int ks = 0; ks < 2; ++ks) {                        \
      _Pragma("unroll") for (int mi = 0; mi < 4; ++mi) {                      \
        i32x4 _af = *(const i32x4*)(_la + ((ks * 8 + wr * 4 + mi) << 10) +    \
                                    (lane << 4));                             \
        acc[mi][0] = __builtin_amdgcn_mfma_i32_32x32x32_i8(                   \
            _af, bset[ks][0], acc[mi][0], 0, 0, 0);                           \
        acc[mi][1] = __builtin_amdgcn_mfma_i32_32x32x32_i8(                   \
            _af, bset[ks][1], acc[mi][1], 0, 0, 0);                           \
      }                                                                       \
    }                                                                         \
  }
#define TILE(kt_, buf_, bcur, bnxt, VMC)                                      \
  {                                                                           \
    STAGE_A((kt_) + 2, ((buf_) + 2) & 3);                                     \
    LOADB((kt_) + 1, bnxt);                                                   \
    asm volatile("s_waitcnt vmcnt(" #VMC ")" ::: "memory");                   \
    COMPUTE(buf_, bcur);                                                      \
    __builtin_amdgcn_s_barrier();                                             \
  }

  // prologue: A(0)->buf0, A(1)->buf1, B(0)->brA; cold drain
  STAGE_A(0, 0);
  STAGE_A(1, 1);
  LOADB(0, brA);
  asm volatile("s_waitcnt vmcnt(0)" ::: "memory");
  __builtin_amdgcn_s_barrier();

  // main: tiles 0..59 (15 x unroll-4), all static buf/breg indices
  for (int it = 0; it < 15; ++it) {
    int kt = it * 4;
    TILE(kt + 0, 0, brA, brB, 8);
    TILE(kt + 1, 1, brB, brA, 8);
    TILE(kt + 2, 2, brA, brB, 8);
    TILE(kt + 3, 3, brB, brA, 8);
  }
  // tail: tiles 60..63
  {
    STAGE_A(62, 2);
    LOADB(61, brB);
    asm volatile("s_waitcnt vmcnt(8)" ::: "memory");
    COMPUTE(0, brA);
    __builtin_amdgcn_s_barrier();

    STAGE_A(63, 3);
    LOADB(62, brA);
    asm volatile("s_waitcnt vmcnt(8)" ::: "memory");
    COMPUTE(1, brB);
    __builtin_amdgcn_s_barrier();

    LOADB(63, brB);
    asm volatile("s_waitcnt vmcnt(4)" ::: "memory");  // confirms B(62)+A(63)
    COMPUTE(2, brA);
    __builtin_amdgcn_s_barrier();

    asm volatile("s_waitcnt vmcnt(0)" ::: "memory");  // B(63)
    COMPUTE(3, brB);
  }

#undef TILE
#undef COMPUTE
#undef LOADB
#undef STAGE_A

  // epilogue: y = s[m] * acc + bias[n]
  // C/D 32x32: col = lane&31, row = (reg&3) + 8*(reg>>2) + 4*(lane>>5)
#pragma unroll
  for (int mi = 0; mi < 4; ++mi) {
#pragma unroll
    for (int ni = 0; ni < 2; ++ni) {
      int gc = colBase + wc * 64 + ni * 32 + l31;
      float bv = bias[gc];
#pragma unroll
      for (int rg = 0; rg < 16; ++rg) {
        int rowIn = (rg & 3) + 8 * (rg >> 2) + 4 * hi;
        int gr = rowBase + wr * 128 + mi * 32 + rowIn;
        C[(size_t)gr * N_TOT + gc] = (float)acc[mi][ni][rg] * s[gr] + bv;
      }
    }
  }
}

// ---------------- fallback (ws too small): fused bf16 conversion GEMM --------
__global__ void gemm_fused_kernel(const float* __restrict__ A,
                                  const float* __restrict__ W,
                                  const float* __restrict__ bias,
                                  float* __restrict__ C) {
  __shared__ ushort lsA[128 * 32];
  __shared__ ushort lsB[128 * 32];

  int nwg = gridDim.x;
  int bid = blockIdx.x;
  int wg = (bid & 7) * (nwg >> 3) + (bid >> 3);
  const int NBN = N_TOT / 128;
  int bm = wg / NBN;
  int bn = wg % NBN;
  int rowBase = bm * 128;
  int colBase = bn * 128;

  int t = threadIdx.x;
  int lane = t & 63;
  int wave = t >> 6;
  int wm = (wave >> 1) * 64;
  int wn = (wave & 1) * 64;

  f32x4 acc[4][4] = {};

  int srow = t >> 3;
  int scol = (t & 7) * 4;
  int fr = lane & 15;
  int koff = (lane >> 4) * 8;

  for (int k0 = 0; k0 < K_TOT; k0 += 32) {
    float4 va[4], vb[4];
#pragma unroll
    for (int r = 0; r < 4; ++r) {
      va[r] = *(const float4*)&A[(size_t)(rowBase + r * 32 + srow) * K_TOT + k0 + scol];
      vb[r] = *(const float4*)&W[(size_t)(colBase + r * 32 + srow) * K_TOT + k0 + scol];
    }
    __syncthreads();
#pragma unroll
    for (int r = 0; r < 4; ++r) {
      int e = r * 1024 + t * 4;
      ushort4 oa, ob;
      oa.x = f2bf_rne(va[r].x); oa.y = f2bf_rne(va[r].y);
      oa.z = f2bf_rne(va[r].z); oa.w = f2bf_rne(va[r].w);
      ob.x = sgn_bf16(vb[r].x); ob.y = sgn_bf16(vb[r].y);
      ob.z = sgn_bf16(vb[r].z); ob.w = sgn_bf16(vb[r].w);
      *(ushort4*)&lsA[e] = oa;
      *(ushort4*)&lsB[e] = ob;
    }
    __syncthreads();

    bf16x8 af[4], bfr[4];
#pragma unroll
    for (int i = 0; i < 4; ++i)
      af[i] = *(const bf16x8*)&lsA[(wm + i * 16 + fr) * 32 + koff];
#pragma unroll
    for (int j = 0; j < 4; ++j)
      bfr[j] = *(const bf16x8*)&lsB[(wn + j * 16 + fr) * 32 + koff];

#pragma unroll
    for (int i = 0; i < 4; ++i)
#pragma unroll
      for (int j = 0; j < 4; ++j)
        acc[i][j] = __builtin_amdgcn_mfma_f32_16x16x32_bf16(af[i], bfr[j],
                                                            acc[i][j], 0, 0, 0);
  }

  int orow0 = rowBase + wm + ((lane >> 4) << 2);
  int ocol0 = colBase + wn + (lane & 15);
#pragma unroll
  for (int i = 0; i < 4; ++i) {
#pragma unroll
    for (int j = 0; j < 4; ++j) {
      int col = ocol0 + j * 16;
      float bv = bias[col];
#pragma unroll
      for (int rg = 0; rg < 4; ++rg) {
        int row = orow0 + i * 16 + rg;
        C[(size_t)row * N_TOT + col] = acc[i][j][rg] + bv;
      }
    }
  }
}

extern "C" void kernel_launch(void* const* d_in, const int* in_sizes, int n_in,
                              void* d_out, int out_size, void* d_ws,
                              size_t ws_size, hipStream_t stream) {
  const float* x = (const float*)d_in[0];
  const float* W = (const float*)d_in[1];
  const float* b = (const float*)d_in[2];
  float* out = (float*)d_out;

  const size_t xq_bytes = (size_t)M_TOT * K_TOT;           // 33.5 MB
  const size_t wq_bytes = (size_t)N_TOT * K_TOT;           // 67.1 MB
  const size_t need = xq_bytes + wq_bytes + M_TOT * 4;     // ~101 MB

  if (ws_size >= need) {
    char* At = (char*)d_ws;
    char* Bt = At + xq_bytes;
    float* s = (float*)(Bt + wq_bytes);
    quant_x_kernel<<<M_TOT, 256, 0, stream>>>(x, At, s);
    quant_w_kernel<<<N_TOT / 32, 256, 0, stream>>>(W, Bt);
    const int nblocks = (M_TOT / BM) * (N_TOT / BN);  // 4096
    gemm_i8_reg<<<nblocks, 256, 0, stream>>>(At, Bt, s, b, out);
  } else {
    const int nblocks = (M_TOT / 128) * (N_TOT / 128);
    gemm_fused_kernel<<<nblocks, 256, 0, stream>>>(x, W, b, out);
  }
}